// Round 5
// baseline (140.104 us; speedup 1.0000x reference)
//
#include <hip/hip_runtime.h>
#include <math.h>

// AWLoss closed-form: f = 24 - (0.5/511^2) * sum_c S1_c^2 / S2_c
// S1 = sum Re(Fdconv), S2 = sum |Fdconv|^2 over half-spectrum k1 in [0,511),
// k2 in [0,256), weight 1 for k2==0 else 2.
// Fdconv = (conj(X)Y + eps*wbar) / (|X|^2 + eps*wbar), wbar = e^{-2pi i (k1+k2)/511}
// X = DFT2(pad(target)), Y = DFT2(pad(recon)), pad offset 127.
//
// stage1: MFMA GEMM (image x twiddle), writes x1t as 6 bf16 planes per channel:
//         {Xr, Xi, -Xi, Yr, Yi, -Yi} transposed to [k2][n].
// stage2: per block (ch, k2-tile): x1t slice staged to LDS once (48KB);
//         4 acc chains (Xr,Xi,Yr,Yi) via negated-plane complex MFMA;
//         w2f twiddle fragments streamed from L2 with deep ILP;
//         wbar computed by incremental per-lane rotation (no LDS table).
// Single twiddle fragment table w2f serves both stages (k2 slice == k1<256 slice).

#define NCH 48
#define PADOFF 127
#define TWO_PI_F 6.283185307179586f
#define EPSV 1e-9f

typedef float f32x4 __attribute__((ext_vector_type(4)));
typedef short s16x8 __attribute__((ext_vector_type(8)));
typedef unsigned short u16;

union frag_u { u16 u[8]; s16x8 v; };

__device__ __forceinline__ u16 f2bf(float f) {
    union { float f; unsigned u; } x; x.f = f;
    unsigned r = x.u + 0x7FFFu + ((x.u >> 16) & 1u);
    return (u16)(r >> 16);
}

// ---------------- setup: twiddle fragment table + acc zero ----------------
// w2f : fragments [kt(32)][c(2)][kk(8)][lane(64)][j(8)] bf16
//       element: twiddle((16kt + (l&15)) * (32kk + 8(l>>4) + j + 127) mod 511),
//       c=0 cos, c=1 sin; rows k1>=511 zeroed.
__global__ __launch_bounds__(256) void setup(u16* __restrict__ w2f,
                                             float* __restrict__ sacc) {
    __shared__ float cs[511], sn[511];
    int tid = threadIdx.x;
    for (int i = tid; i < 511; i += 256) {
        float a = -TWO_PI_F * (float)i / 511.0f;
        cs[i] = cosf(a);
        sn[i] = sinf(a);
    }
    __syncthreads();

    int i = blockIdx.x * 256 + tid;      // i < 262144
    int j = i & 7, l = (i >> 3) & 63, kk = (i >> 9) & 7;
    int c = (i >> 12) & 1, kt = i >> 13;
    int k1 = 16 * kt + (l & 15);
    u16 v = 0;
    if (k1 < 511) {
        int n = 32 * kk + 8 * (l >> 4) + j;
        int p = (k1 * (n + PADOFF)) % 511;
        v = f2bf(c ? sn[p] : cs[p]);
    }
    w2f[i] = v;
    if (blockIdx.x == 0 && tid < 2 * NCH) sacc[tid] = 0.0f;
}

// ---------------- stage 1: DFT along W (MFMA) ----------------
// X1[n1][k2] = sum_b src[n1][b] * W[b][k2]; stored transposed bf16, 3 planes
// per image {re, im, -im}: x1t[img*3 + plane][k2][n1]. grid = cc*2 images x 16 mt.
__global__ __launch_bounds__(256) void stage1(const float* __restrict__ target,
                                              const float* __restrict__ recon,
                                              const u16* __restrict__ w2f,
                                              u16* __restrict__ x1t,
                                              int c0) {
    int bid = blockIdx.x;
    int img_local = bid >> 4;
    int mt = bid & 15;
    int lc = img_local >> 1;
    int tsel = img_local & 1;
    const float* src = (tsel == 0 ? target : recon) + (size_t)(c0 + lc) * 65536;

    int tid = threadIdx.x;
    int w = tid >> 6, l = tid & 63;
    int lm = l & 15, lh = l >> 4;

    frag_u af[8];
    const float* ap = src + (size_t)(mt * 16 + lm) * 256 + 8 * lh;
    #pragma unroll
    for (int kk = 0; kk < 8; ++kk) {
        float4 v0 = *(const float4*)(ap + 32 * kk);
        float4 v1 = *(const float4*)(ap + 32 * kk + 4);
        af[kk].u[0] = f2bf(v0.x); af[kk].u[1] = f2bf(v0.y);
        af[kk].u[2] = f2bf(v0.z); af[kk].u[3] = f2bf(v0.w);
        af[kk].u[4] = f2bf(v1.x); af[kk].u[5] = f2bf(v1.y);
        af[kk].u[6] = f2bf(v1.z); af[kk].u[7] = f2bf(v1.w);
    }

    #pragma unroll
    for (int t4 = 0; t4 < 4; ++t4) {
        int t = 4 * w + t4;
        #pragma unroll
        for (int c = 0; c < 2; ++c) {
            f32x4 acc = {0.f, 0.f, 0.f, 0.f};
            // shared table: w2f[kt=t][c] slice == stage1 twiddles for k2-tile t
            const u16* wp = w2f + ((size_t)(t * 2 + c)) * 4096 + l * 8;
            #pragma unroll
            for (int kk = 0; kk < 8; ++kk) {
                s16x8 b = *(const s16x8*)(wp + kk * 512);
                acc = __builtin_amdgcn_mfma_f32_16x16x32_bf16(af[kk].v, b, acc, 0, 0, 0);
            }
            ushort4 o;
            o.x = f2bf(acc[0]); o.y = f2bf(acc[1]);
            o.z = f2bf(acc[2]); o.w = f2bf(acc[3]);
            u16* dst = x1t + ((size_t)img_local * 3 + c) * 65536
                     + (size_t)(16 * t + lm) * 256 + 16 * mt + 4 * lh;
            *(ushort4*)dst = o;
            if (c == 1) {                      // negated-imag plane
                ushort4 no;
                no.x = o.x ^ 0x8000; no.y = o.y ^ 0x8000;
                no.z = o.z ^ 0x8000; no.w = o.w ^ 0x8000;
                *(ushort4*)(dst + 65536) = no;
            }
        }
    }
}

// ---------------- stage 2: DFT along H (MFMA) + pointwise + reduce ----------------
// grid = cc channels x 16 k2-tiles, 4 waves. x1t slice (6 planes x 8kk x 1KB)
// staged to LDS once; each wave covers kt = 8w..8w+7, streaming w2f.
__global__ __launch_bounds__(256, 3) void stage2(const u16* __restrict__ x1t,
                                                 const u16* __restrict__ w2f,
                                                 float* __restrict__ sacc,
                                                 int c0) {
    int lc = blockIdx.x >> 4;
    int t  = blockIdx.x & 15;
    int tid = threadIdx.x;
    int w = tid >> 6, l = tid & 63;
    int lm = l & 15, lh = l >> 4;

    __shared__ u16 fr[6 * 8 * 512];       // 48 KiB: [plane][kk][lane*8]
    __shared__ float red[8];

    // ---- stage x1t slice into LDS (fragment-linear; write order == read order)
    const u16* chbase = x1t + (size_t)lc * 6 * 65536;
    int rowbase = 16 * t + lm;
    #pragma unroll
    for (int q = 0; q < 12; ++q) {
        int cid = w * 12 + q;             // 0..47 = plane*8 + kk
        int p = cid >> 3, kk = cid & 7;
        const u16* g = chbase + (size_t)p * 65536 + (size_t)rowbase * 256
                     + 32 * kk + 8 * lh;
        *(s16x8*)&fr[(size_t)cid * 512 + l * 8] = *(const s16x8*)g;
    }
    __syncthreads();

    int k2 = 16 * t + lm;
    float wgt = (k2 == 0) ? 1.f : 2.f;
    float s1 = 0.f, s2 = 0.f;

    // incremental wbar = e^{-2pi i (k1+k2)/511}; p = b0 + 16*i8 + r
    const float R1c  = cosf(TWO_PI_F / 511.0f);
    const float R1s  = -sinf(TWO_PI_F / 511.0f);
    const float R16c = cosf(16.0f * TWO_PI_F / 511.0f);
    const float R16s = -sinf(16.0f * TWO_PI_F / 511.0f);
    float b0 = (float)(128 * w + 4 * lh + k2);
    float th = -(TWO_PI_F / 511.0f) * b0;
    float cb = cosf(th), sb = sinf(th);

    for (int i8 = 0; i8 < 8; ++i8) {
        int kt = 8 * w + i8;
        const u16* wp = w2f + (size_t)kt * 8192 + l * 8;
        f32x4 xr = {0,0,0,0}, xi = {0,0,0,0}, yr = {0,0,0,0}, yi = {0,0,0,0};
        #pragma unroll
        for (int kk = 0; kk < 8; ++kk) {
            s16x8 wr = *(const s16x8*)(wp + kk * 512);
            s16x8 wi = *(const s16x8*)(wp + 4096 + kk * 512);
            const u16* fb = &fr[kk * 512 + l * 8];
            s16x8 ar  = *(const s16x8*)(fb);
            s16x8 ai  = *(const s16x8*)(fb + 4096);
            s16x8 nai = *(const s16x8*)(fb + 8192);
            s16x8 br  = *(const s16x8*)(fb + 12288);
            s16x8 bi  = *(const s16x8*)(fb + 16384);
            s16x8 nbi = *(const s16x8*)(fb + 20480);
            xr = __builtin_amdgcn_mfma_f32_16x16x32_bf16(wr, ar,  xr, 0, 0, 0);
            xr = __builtin_amdgcn_mfma_f32_16x16x32_bf16(wi, nai, xr, 0, 0, 0);
            xi = __builtin_amdgcn_mfma_f32_16x16x32_bf16(wr, ai,  xi, 0, 0, 0);
            xi = __builtin_amdgcn_mfma_f32_16x16x32_bf16(wi, ar,  xi, 0, 0, 0);
            yr = __builtin_amdgcn_mfma_f32_16x16x32_bf16(wr, br,  yr, 0, 0, 0);
            yr = __builtin_amdgcn_mfma_f32_16x16x32_bf16(wi, nbi, yr, 0, 0, 0);
            yi = __builtin_amdgcn_mfma_f32_16x16x32_bf16(wr, bi,  yi, 0, 0, 0);
            yi = __builtin_amdgcn_mfma_f32_16x16x32_bf16(wi, br,  yi, 0, 0, 0);
        }
        float cr = cb, si_ = sb;
        #pragma unroll
        for (int r = 0; r < 4; ++r) {
            int k1 = 16 * kt + 4 * lh + r;
            float wg2 = (k1 < 511) ? wgt : 0.f;
            float Xr = xr[r], Xi = xi[r], Yr = yr[r], Yi = yi[r];
            float Pr = Xr * Yr + Xi * Yi;
            float Pi = Xr * Yi - Xi * Yr;
            float Q  = Xr * Xr + Xi * Xi;
            float nr = Pr + EPSV * cr;
            float ni = Pi + EPSV * si_;
            float dr_ = Q + EPSV * cr;
            float di_ = EPSV * si_;
            float inv = 1.0f / (dr_ * dr_ + di_ * di_);
            s1 += wg2 * (nr * dr_ + ni * di_) * inv;
            s2 += wg2 * (nr * nr + ni * ni) * inv;
            float cn = cr * R1c - si_ * R1s;   // rotate wbar by R1
            si_ = cr * R1s + si_ * R1c; cr = cn;
        }
        float cn = cb * R16c - sb * R16s;       // advance base by R16
        sb = cb * R16s + sb * R16c; cb = cn;
    }

    #pragma unroll
    for (int off = 32; off > 0; off >>= 1) {
        s1 += __shfl_down(s1, off);
        s2 += __shfl_down(s2, off);
    }
    if (l == 0) { red[w] = s1; red[4 + w] = s2; }
    __syncthreads();
    if (tid == 0) {
        float a1 = red[0] + red[1] + red[2] + red[3];
        float a2 = red[4] + red[5] + red[6] + red[7];
        atomicAdd(&sacc[c0 + lc], a1);
        atomicAdd(&sacc[NCH + c0 + lc], a2);
    }
}

__global__ void finalize(const float* __restrict__ s, float* __restrict__ out) {
    int t = threadIdx.x;
    float v = 0.f;
    if (t < NCH) {
        float s1 = s[t], s2 = s[NCH + t];
        v = (s2 != 0.f) ? (s1 * s1) / s2 : 0.f;
    }
    for (int off = 32; off > 0; off >>= 1) v += __shfl_down(v, off);
    if (t == 0) out[0] = 24.0f - 0.5f * v / 261121.0f;
}

// ---------------- launch ----------------
extern "C" void kernel_launch(void* const* d_in, const int* in_sizes, int n_in,
                              void* d_out, int out_size, void* d_ws, size_t ws_size,
                              hipStream_t stream) {
    const float* recon  = (const float*)d_in[0];
    const float* target = (const float*)d_in[1];
    float* out = (float*)d_out;
    char* ws = (char*)d_ws;

    const size_t OFF_W2F = 0;                        // 524288 B
    const size_t OFF_S   = OFF_W2F + 524288;         // 512 B
    const size_t OFF_X1  = OFF_S + 512;

    u16*   w2f  = (u16*)(ws + OFF_W2F);
    float* sacc = (float*)(ws + OFF_S);
    u16*   x1t  = (u16*)(ws + OFF_X1);

    const size_t perch = 6ull * 65536 * 2;           // 768 KiB per channel
    size_t avail = (ws_size > OFF_X1) ? ws_size - OFF_X1 : 0;
    int chunk = (int)(avail / perch);
    if (chunk > NCH) chunk = NCH;
    if (chunk < 1) chunk = 1;

    setup<<<dim3(1024), dim3(256), 0, stream>>>(w2f, sacc);

    for (int c0 = 0; c0 < NCH; c0 += chunk) {
        int cc = (NCH - c0 < chunk) ? (NCH - c0) : chunk;
        stage1<<<dim3(cc * 32), dim3(256), 0, stream>>>(target, recon, w2f, x1t, c0);
        stage2<<<dim3(cc * 16), dim3(256), 0, stream>>>(x1t, w2f, sacc, c0);
    }
    finalize<<<dim3(1), dim3(64), 0, stream>>>(sacc, out);
}

// Round 6
// 85.935 us; speedup vs baseline: 1.6303x; 1.6303x over previous
//
#include <hip/hip_runtime.h>
#include <math.h>

// AWLoss closed-form: f = 24 - (0.5/511^2) * sum_c S1_c^2 / S2_c
// S1 = sum wgt*Re(F), S2 = sum wgt*|F|^2 over half-spectrum k1 in [0,511),
// k2 in [0,256), wgt = 1 for k2==0 else 2, F = conj(X)Y / |X|^2
// (the 1e-9 pre-whitening term is < 1e-12 relative to |X|^2 ~ 1e4 -> dropped).
// X = DFT2(pad(target)), Y = DFT2(pad(recon)), pad offset 127.
//
// stage1: MFMA GEMM rows->freq, writes x1t 4 bf16 planes {Xr,Xi,Yr,Yi} as [k2][n].
// stage2: 768 wave-tasks (ch, k2-tile); each wave holds its x1t frags
//         register-stationary (asm-pinned) and walks all 32 kt tiles, the 4
//         waves of a block sharing the streamed w2f twiddle fragments
//         (same addresses -> L1 broadcast), double-buffered in registers.
// One twiddle fragment table w2f serves both stages (stage1 t-slice == kt<16).

#define NCH 48
#define PADOFF 127
#define TWO_PI_F 6.283185307179586f

typedef float f32x4 __attribute__((ext_vector_type(4)));
typedef short s16x8 __attribute__((ext_vector_type(8)));
typedef unsigned short u16;

union frag_u { u16 u[8]; s16x8 v; };

__device__ __forceinline__ u16 f2bf(float f) {
    union { float f; unsigned u; } x; x.f = f;
    unsigned r = x.u + 0x7FFFu + ((x.u >> 16) & 1u);
    return (u16)(r >> 16);
}

#define MFMA16(A, B, C) __builtin_amdgcn_mfma_f32_16x16x32_bf16(A, B, C, 0, 0, 0)

// ---------------- setup: twiddle fragment table + acc zero ----------------
// w2f : fragments [kt(32)][c(2)][kk(8)][lane(64)][j(8)] bf16
//       element: tw((16kt + (l&15)) * (32kk + 8(l>>4) + j + 127) mod 511),
//       c=0 cos, c=1 sin; row k1==511 zeroed.
__global__ __launch_bounds__(256) void setup(u16* __restrict__ w2f,
                                             float* __restrict__ sacc) {
    __shared__ float cs[511], sn[511];
    int tid = threadIdx.x;
    for (int i = tid; i < 511; i += 256) {
        float a = -TWO_PI_F * (float)i / 511.0f;
        cs[i] = cosf(a);
        sn[i] = sinf(a);
    }
    __syncthreads();

    int i = blockIdx.x * 256 + tid;      // i < 262144
    int j = i & 7, l = (i >> 3) & 63, kk = (i >> 9) & 7;
    int c = (i >> 12) & 1, kt = i >> 13;
    int k1 = 16 * kt + (l & 15);
    u16 v = 0;
    if (k1 < 511) {
        int n = 32 * kk + 8 * (l >> 4) + j;
        int p = (k1 * (n + PADOFF)) % 511;
        v = f2bf(c ? sn[p] : cs[p]);
    }
    w2f[i] = v;
    if (blockIdx.x == 0 && tid < 2 * NCH) sacc[tid] = 0.0f;
}

// ---------------- stage 1: DFT along W (MFMA) ----------------
// X1[n1][k2] = sum_b src[n1][b] * W[b][k2]; x1t[lc*4 + tsel*2 + c][k2][n1] bf16.
// grid = cc*8 blocks: img = bid>>2 (2cc images), q = bid&3; wave w owns
// mt = 4q + w (rows 16mt..16mt+15); waves share the w2f t-stream.
__global__ __launch_bounds__(256, 3) void stage1(const float* __restrict__ target,
                                                 const float* __restrict__ recon,
                                                 const u16* __restrict__ w2f,
                                                 u16* __restrict__ x1t,
                                                 int c0) {
    int bid = blockIdx.x;
    int img = bid >> 2;                 // [0, 2cc)
    int q   = bid & 3;
    int lc  = img >> 1;
    int tsel = img & 1;
    const float* src = (tsel == 0 ? target : recon) + (size_t)(c0 + lc) * 65536;

    int tid = threadIdx.x;
    int w = tid >> 6, l = tid & 63;
    int lm = l & 15, lh = l >> 4;
    int mt = 4 * q + w;

    // A fragments: 16 rows of this mt-tile, full K=256, f32 -> bf16
    frag_u af[8];
    const float* ap = src + (size_t)(mt * 16 + lm) * 256 + 8 * lh;
    #pragma unroll
    for (int kk = 0; kk < 8; ++kk) {
        float4 v0 = *(const float4*)(ap + 32 * kk);
        float4 v1 = *(const float4*)(ap + 32 * kk + 4);
        af[kk].u[0] = f2bf(v0.x); af[kk].u[1] = f2bf(v0.y);
        af[kk].u[2] = f2bf(v0.z); af[kk].u[3] = f2bf(v0.w);
        af[kk].u[4] = f2bf(v1.x); af[kk].u[5] = f2bf(v1.y);
        af[kk].u[6] = f2bf(v1.z); af[kk].u[7] = f2bf(v1.w);
    }

    u16* chdst = x1t + (size_t)(lc * 4 + tsel * 2) * 65536;

    #pragma unroll 2
    for (int t = 0; t < 16; ++t) {
        const u16* wp = w2f + (size_t)t * 8192 + l * 8;
        f32x4 acc0 = {0.f, 0.f, 0.f, 0.f};
        f32x4 acc1 = {0.f, 0.f, 0.f, 0.f};
        #pragma unroll
        for (int kk = 0; kk < 8; ++kk) {
            s16x8 bc = *(const s16x8*)(wp + kk * 512);          // cos
            s16x8 bs = *(const s16x8*)(wp + 4096 + kk * 512);   // sin
            acc0 = MFMA16(af[kk].v, bc, acc0);
            acc1 = MFMA16(af[kk].v, bs, acc1);
        }
        // D element (m = 4lh+r, n = lm): n1 = 16mt+4lh+r, k2 = 16t+lm
        ushort4 o0, o1;
        o0.x = f2bf(acc0[0]); o0.y = f2bf(acc0[1]);
        o0.z = f2bf(acc0[2]); o0.w = f2bf(acc0[3]);
        o1.x = f2bf(acc1[0]); o1.y = f2bf(acc1[1]);
        o1.z = f2bf(acc1[2]); o1.w = f2bf(acc1[3]);
        size_t off = (size_t)(16 * t + lm) * 256 + 16 * mt + 4 * lh;
        *(ushort4*)(chdst + off)         = o0;   // re plane
        *(ushort4*)(chdst + 65536 + off) = o1;   // im plane
    }
}

// ---------------- stage 2: DFT along H (MFMA) + pointwise + reduce ----------------
// grid = cc*4 blocks x 4 waves; wave task = (lc, t) from flat id.
// Frags register-stationary; all waves iterate kt together sharing w2f.
__global__ __launch_bounds__(256, 1) void stage2(const u16* __restrict__ x1t,
                                                 const u16* __restrict__ w2f,
                                                 float* __restrict__ sacc,
                                                 int c0) {
    int tid = threadIdx.x;
    int w = tid >> 6, l = tid & 63;
    int lm = l & 15, lh = l >> 4;
    int task = blockIdx.x * 4 + w;      // [0, cc*16)
    int lc = task >> 4;
    int t  = task & 15;

    const u16* base = x1t + (size_t)(4 * lc) * 65536;   // planes Xr,Xi,Yr,Yi
    size_t roff = (size_t)(16 * t + lm) * 256 + 8 * lh;

    // B fragments: this wave's (ch, k2-tile), full K, register-stationary
    s16x8 ar[8], ai[8], br[8], bi[8];
    #pragma unroll
    for (int kk = 0; kk < 8; ++kk) {
        size_t off = roff + 32 * kk;
        ar[kk] = *(const s16x8*)(base + off);
        ai[kk] = *(const s16x8*)(base + 65536 + off);
        br[kk] = *(const s16x8*)(base + 131072 + off);
        bi[kk] = *(const s16x8*)(base + 196608 + off);
    }
    #pragma unroll
    for (int kk = 0; kk < 8; ++kk)
        asm volatile("" : "+v"(ar[kk]), "+v"(ai[kk]), "+v"(br[kk]), "+v"(bi[kk]));

    int k2 = 16 * t + lm;
    float wgt = (k2 == 0) ? 1.f : 2.f;
    float s1 = 0.f, s2 = 0.f;

#define LOADW(WR, WI, KT) do {                                              \
    const u16* wp_ = w2f + (size_t)(KT) * 8192 + l * 8;                     \
    _Pragma("unroll")                                                       \
    for (int kk = 0; kk < 8; ++kk) {                                        \
        WR[kk] = *(const s16x8*)(wp_ + kk * 512);                           \
        WI[kk] = *(const s16x8*)(wp_ + 4096 + kk * 512);                    \
    } } while (0)

#define COMPUTE(WR, WI, KT) do {                                            \
    f32x4 crr = {0,0,0,0}, cii = {0,0,0,0}, cri = {0,0,0,0}, cir = {0,0,0,0}; \
    f32x4 drr = {0,0,0,0}, dii = {0,0,0,0}, dri = {0,0,0,0}, dir = {0,0,0,0}; \
    _Pragma("unroll")                                                       \
    for (int kk = 0; kk < 8; ++kk) {                                        \
        crr = MFMA16(WR[kk], ar[kk], crr);                                  \
        cii = MFMA16(WI[kk], ai[kk], cii);                                  \
        cri = MFMA16(WR[kk], ai[kk], cri);                                  \
        cir = MFMA16(WI[kk], ar[kk], cir);                                  \
        drr = MFMA16(WR[kk], br[kk], drr);                                  \
        dii = MFMA16(WI[kk], bi[kk], dii);                                  \
        dri = MFMA16(WR[kk], bi[kk], dri);                                  \
        dir = MFMA16(WI[kk], br[kk], dir);                                  \
    }                                                                       \
    _Pragma("unroll")                                                       \
    for (int r = 0; r < 4; ++r) {                                           \
        int k1_ = 16 * (KT) + 4 * lh + r;                                   \
        float wg2 = (k1_ < 511) ? wgt : 0.f;                                \
        float Xr = crr[r] - cii[r], Xi = cri[r] + cir[r];                   \
        float Yr = drr[r] - dii[r], Yi = dri[r] + dir[r];                   \
        float Pr = Xr * Yr + Xi * Yi;                                       \
        float Pi = Xr * Yi - Xi * Yr;                                       \
        float Q  = Xr * Xr + Xi * Xi;                                       \
        float inv = 1.0f / (Q * Q + 1e-30f);                                \
        s1 += wg2 * Pr * Q * inv;                                           \
        s2 += wg2 * (Pr * Pr + Pi * Pi) * inv;                              \
    } } while (0)

    s16x8 wrA[8], wiA[8], wrB[8], wiB[8];
    LOADW(wrA, wiA, 0);
    for (int kt = 0; kt < 32; kt += 2) {
        LOADW(wrB, wiB, kt + 1);
        COMPUTE(wrA, wiA, kt);
        if (kt + 2 < 32) LOADW(wrA, wiA, kt + 2);
        COMPUTE(wrB, wiB, kt + 1);
    }
#undef LOADW
#undef COMPUTE

    #pragma unroll
    for (int off = 32; off > 0; off >>= 1) {
        s1 += __shfl_down(s1, off);
        s2 += __shfl_down(s2, off);
    }
    if (l == 0) {
        atomicAdd(&sacc[c0 + lc], s1);
        atomicAdd(&sacc[NCH + c0 + lc], s2);
    }
}

__global__ void finalize(const float* __restrict__ s, float* __restrict__ out) {
    int t = threadIdx.x;
    float v = 0.f;
    if (t < NCH) {
        float s1 = s[t], s2 = s[NCH + t];
        v = (s2 != 0.f) ? (s1 * s1) / s2 : 0.f;
    }
    for (int off = 32; off > 0; off >>= 1) v += __shfl_down(v, off);
    if (t == 0) out[0] = 24.0f - 0.5f * v / 261121.0f;
}

// ---------------- launch ----------------
extern "C" void kernel_launch(void* const* d_in, const int* in_sizes, int n_in,
                              void* d_out, int out_size, void* d_ws, size_t ws_size,
                              hipStream_t stream) {
    const float* recon  = (const float*)d_in[0];
    const float* target = (const float*)d_in[1];
    float* out = (float*)d_out;
    char* ws = (char*)d_ws;

    const size_t OFF_W2F = 0;                        // 524288 B
    const size_t OFF_S   = OFF_W2F + 524288;         // 512 B
    const size_t OFF_X1  = OFF_S + 512;

    u16*   w2f  = (u16*)(ws + OFF_W2F);
    float* sacc = (float*)(ws + OFF_S);
    u16*   x1t  = (u16*)(ws + OFF_X1);

    const size_t perch = 4ull * 65536 * 2;           // 512 KiB per channel
    size_t avail = (ws_size > OFF_X1) ? ws_size - OFF_X1 : 0;
    int chunk = (int)(avail / perch);
    if (chunk > NCH) chunk = NCH;
    if (chunk < 1) chunk = 1;

    setup<<<dim3(1024), dim3(256), 0, stream>>>(w2f, sacc);

    for (int c0 = 0; c0 < NCH; c0 += chunk) {
        int cc = (NCH - c0 < chunk) ? (NCH - c0) : chunk;
        stage1<<<dim3(cc * 8), dim3(256), 0, stream>>>(target, recon, w2f, x1t, c0);
        stage2<<<dim3(cc * 4), dim3(256), 0, stream>>>(x1t, w2f, sacc, c0);
    }
    finalize<<<dim3(1), dim3(64), 0, stream>>>(sacc, out);
}

// Round 7
// 71.734 us; speedup vs baseline: 1.9531x; 1.1980x over previous
//
#include <hip/hip_runtime.h>
#include <math.h>

// AWLoss closed-form: f = 24 - (0.5/511^2) * sum_c S1_c^2 / S2_c
// S1 = sum wgt*Re(F), S2 = sum wgt*|F|^2 over half-spectrum k1 in [0,511),
// k2 in [0,256), wgt = 1 for k2==0 else 2, F = conj(X)Y / |X|^2
// (1e-9 pre-whitening is < 1e-12 relative to |X|^2 ~ 1e4 -> dropped).
// X = DFT2(pad(target)), Y = DFT2(pad(recon)), pad offset 127.
//
// stage1: MFMA GEMM rows->freq; wave owns 32 rows (2 sub-tiles), walks 16
//         k2-tiles with double-buffered twiddle fragments.
// stage2: 768 wave-tasks (ch, k2-tile); x1t frags pinned in AGPRs (MFMA can
//         read A/B operands from AGPRs on gfx950), w2f twiddles streamed
//         through a true VGPR double buffer.
// One twiddle fragment table w2f serves both stages.

#define NCH 48
#define PADOFF 127
#define TWO_PI_F 6.283185307179586f

typedef float f32x4 __attribute__((ext_vector_type(4)));
typedef short s16x8 __attribute__((ext_vector_type(8)));
typedef unsigned short u16;

union frag_u { u16 u[8]; s16x8 v; };

__device__ __forceinline__ u16 f2bf(float f) {
    union { float f; unsigned u; } x; x.f = f;
    unsigned r = x.u + 0x7FFFu + ((x.u >> 16) & 1u);
    return (u16)(r >> 16);
}

#define MFMA16(A, B, C) __builtin_amdgcn_mfma_f32_16x16x32_bf16(A, B, C, 0, 0, 0)

// ---------------- setup: twiddle fragment table + acc zero ----------------
// w2f : fragments [kt(32)][c(2)][kk(8)][lane(64)][j(8)] bf16
//       element: tw((16kt + (l&15)) * (32kk + 8(l>>4) + j + 127) mod 511),
//       c=0 cos, c=1 sin; row k1==511 zeroed.
__global__ __launch_bounds__(256) void setup(u16* __restrict__ w2f,
                                             float* __restrict__ sacc) {
    __shared__ float cs[511], sn[511];
    int tid = threadIdx.x;
    for (int i = tid; i < 511; i += 256) {
        float a = -TWO_PI_F * (float)i / 511.0f;
        cs[i] = cosf(a);
        sn[i] = sinf(a);
    }
    __syncthreads();

    int i = blockIdx.x * 256 + tid;      // i < 262144
    int j = i & 7, l = (i >> 3) & 63, kk = (i >> 9) & 7;
    int c = (i >> 12) & 1, kt = i >> 13;
    int k1 = 16 * kt + (l & 15);
    u16 v = 0;
    if (k1 < 511) {
        int n = 32 * kk + 8 * (l >> 4) + j;
        int p = (k1 * (n + PADOFF)) % 511;
        v = f2bf(c ? sn[p] : cs[p]);
    }
    w2f[i] = v;
    if (blockIdx.x == 0 && tid < 2 * NCH) sacc[tid] = 0.0f;
}

// ---------------- stage 1: DFT along W (MFMA) ----------------
// X1[n1][k2] = sum_b src[n1][b] * W[b][k2]; x1t[lc*4 + tsel*2 + c][k2][n1] bf16.
// grid = cc*4 blocks x 4 waves; wave task = (img, mp): rows 32mp..32mp+31.
// Twiddle fragments double-buffered over the 16 k2-tiles.
__global__ __launch_bounds__(256, 1) void stage1(const float* __restrict__ target,
                                                 const float* __restrict__ recon,
                                                 const u16* __restrict__ w2f,
                                                 u16* __restrict__ x1t,
                                                 int c0) {
    int tid = threadIdx.x;
    int w = tid >> 6, l = tid & 63;
    int lm = l & 15, lh = l >> 4;
    int flat = blockIdx.x * 4 + w;       // [0, 2cc*8)
    int img = flat >> 3;
    int mp  = flat & 7;
    int lc = img >> 1;
    int tsel = img & 1;
    const float* src = (tsel == 0 ? target : recon) + (size_t)(c0 + lc) * 65536;

    // A fragments: 32 rows (2 sub-tiles of 16), full K=256, f32 -> bf16
    frag_u af[2][8];
    #pragma unroll
    for (int a = 0; a < 2; ++a) {
        const float* ap = src + (size_t)(32 * mp + 16 * a + lm) * 256 + 8 * lh;
        #pragma unroll
        for (int kk = 0; kk < 8; ++kk) {
            float4 v0 = *(const float4*)(ap + 32 * kk);
            float4 v1 = *(const float4*)(ap + 32 * kk + 4);
            af[a][kk].u[0] = f2bf(v0.x); af[a][kk].u[1] = f2bf(v0.y);
            af[a][kk].u[2] = f2bf(v0.z); af[a][kk].u[3] = f2bf(v0.w);
            af[a][kk].u[4] = f2bf(v1.x); af[a][kk].u[5] = f2bf(v1.y);
            af[a][kk].u[6] = f2bf(v1.z); af[a][kk].u[7] = f2bf(v1.w);
        }
    }

    u16* chdst = x1t + (size_t)(lc * 4 + tsel * 2) * 65536;

#define LD1(BC, BS, T) do {                                                 \
    const u16* wp_ = w2f + (size_t)(T) * 8192 + l * 8;                      \
    _Pragma("unroll")                                                       \
    for (int kk = 0; kk < 8; ++kk) {                                        \
        BC[kk] = *(const s16x8*)(wp_ + kk * 512);                           \
        BS[kk] = *(const s16x8*)(wp_ + 4096 + kk * 512);                    \
    } } while (0)

#define C1(BC, BS, T) do {                                                  \
    _Pragma("unroll")                                                       \
    for (int a = 0; a < 2; ++a) {                                           \
        f32x4 ac = {0,0,0,0}, as_ = {0,0,0,0};                              \
        _Pragma("unroll")                                                   \
        for (int kk = 0; kk < 8; ++kk) {                                    \
            ac  = MFMA16(af[a][kk].v, BC[kk], ac);                          \
            as_ = MFMA16(af[a][kk].v, BS[kk], as_);                         \
        }                                                                   \
        ushort4 o0, o1;                                                     \
        o0.x = f2bf(ac[0]);  o0.y = f2bf(ac[1]);                            \
        o0.z = f2bf(ac[2]);  o0.w = f2bf(ac[3]);                            \
        o1.x = f2bf(as_[0]); o1.y = f2bf(as_[1]);                           \
        o1.z = f2bf(as_[2]); o1.w = f2bf(as_[3]);                           \
        size_t off_ = (size_t)(16 * (T) + lm) * 256 + 32 * mp + 16 * a + 4 * lh; \
        *(ushort4*)(chdst + off_)         = o0;                             \
        *(ushort4*)(chdst + 65536 + off_) = o1;                             \
    } } while (0)

    s16x8 bcA[8], bsA[8], bcB[8], bsB[8];
    LD1(bcA, bsA, 0);
    for (int t = 0; t < 16; t += 2) {
        LD1(bcB, bsB, t + 1);
        C1(bcA, bsA, t);
        if (t + 2 < 16) LD1(bcA, bsA, t + 2);
        C1(bcB, bsB, t + 1);
    }
#undef LD1
#undef C1
}

// ---------------- stage 2: DFT along H (MFMA) + pointwise + reduce ----------------
// grid = cc*4 blocks x 4 waves; wave task = (lc, t). Frags AGPR-stationary;
// all waves iterate kt together sharing the w2f stream (VGPR double buffer).
__global__ __launch_bounds__(256, 1) void stage2(const u16* __restrict__ x1t,
                                                 const u16* __restrict__ w2f,
                                                 float* __restrict__ sacc,
                                                 int c0) {
    int tid = threadIdx.x;
    int w = tid >> 6, l = tid & 63;
    int lm = l & 15, lh = l >> 4;
    int task = blockIdx.x * 4 + w;      // [0, cc*16)
    int lc = task >> 4;
    int t  = task & 15;

    const u16* base = x1t + (size_t)(4 * lc) * 65536;   // planes Xr,Xi,Yr,Yi
    size_t roff = (size_t)(16 * t + lm) * 256 + 8 * lh;

    // B fragments: this wave's (ch, k2-tile), full K, pinned in AGPRs so the
    // VGPR budget is free for the w2f double buffer (round-6 lesson: "+v"
    // pinning starved the DB and serialized the stream).
    s16x8 ar[8], ai[8], br[8], bi[8];
    #pragma unroll
    for (int kk = 0; kk < 8; ++kk) {
        size_t off = roff + 32 * kk;
        ar[kk] = *(const s16x8*)(base + off);
        ai[kk] = *(const s16x8*)(base + 65536 + off);
        br[kk] = *(const s16x8*)(base + 131072 + off);
        bi[kk] = *(const s16x8*)(base + 196608 + off);
    }
    #pragma unroll
    for (int kk = 0; kk < 8; ++kk)
        asm volatile("" : "+a"(ar[kk]), "+a"(ai[kk]), "+a"(br[kk]), "+a"(bi[kk]));

    int k2 = 16 * t + lm;
    float wgt = (k2 == 0) ? 1.f : 2.f;
    float s1 = 0.f, s2 = 0.f;

#define LOADW(WR, WI, KT) do {                                              \
    const u16* wp_ = w2f + (size_t)(KT) * 8192 + l * 8;                     \
    _Pragma("unroll")                                                       \
    for (int kk = 0; kk < 8; ++kk) {                                        \
        WR[kk] = *(const s16x8*)(wp_ + kk * 512);                           \
        WI[kk] = *(const s16x8*)(wp_ + 4096 + kk * 512);                    \
    } } while (0)

#define COMPUTE(WR, WI, KT) do {                                            \
    f32x4 crr = {0,0,0,0}, cii = {0,0,0,0}, cri = {0,0,0,0}, cir = {0,0,0,0}; \
    f32x4 drr = {0,0,0,0}, dii = {0,0,0,0}, dri = {0,0,0,0}, dir = {0,0,0,0}; \
    _Pragma("unroll")                                                       \
    for (int kk = 0; kk < 8; ++kk) {                                        \
        crr = MFMA16(WR[kk], ar[kk], crr);                                  \
        cii = MFMA16(WI[kk], ai[kk], cii);                                  \
        cri = MFMA16(WR[kk], ai[kk], cri);                                  \
        cir = MFMA16(WI[kk], ar[kk], cir);                                  \
        drr = MFMA16(WR[kk], br[kk], drr);                                  \
        dii = MFMA16(WI[kk], bi[kk], dii);                                  \
        dri = MFMA16(WR[kk], bi[kk], dri);                                  \
        dir = MFMA16(WI[kk], br[kk], dir);                                  \
    }                                                                       \
    _Pragma("unroll")                                                       \
    for (int r = 0; r < 4; ++r) {                                           \
        int k1_ = 16 * (KT) + 4 * lh + r;                                   \
        float wg2 = (k1_ < 511) ? wgt : 0.f;                                \
        float Xr = crr[r] - cii[r], Xi = cri[r] + cir[r];                   \
        float Yr = drr[r] - dii[r], Yi = dri[r] + dir[r];                   \
        float Pr = Xr * Yr + Xi * Yi;                                       \
        float Pi = Xr * Yi - Xi * Yr;                                       \
        float Q  = Xr * Xr + Xi * Xi;                                       \
        float inv = 1.0f / (Q * Q + 1e-30f);                                \
        s1 += wg2 * Pr * Q * inv;                                           \
        s2 += wg2 * (Pr * Pr + Pi * Pi) * inv;                              \
    } } while (0)

    s16x8 wrA[8], wiA[8], wrB[8], wiB[8];
    LOADW(wrA, wiA, 0);
    for (int kt = 0; kt < 32; kt += 2) {
        LOADW(wrB, wiB, kt + 1);
        COMPUTE(wrA, wiA, kt);
        if (kt + 2 < 32) LOADW(wrA, wiA, kt + 2);
        COMPUTE(wrB, wiB, kt + 1);
    }
#undef LOADW
#undef COMPUTE

    #pragma unroll
    for (int off = 32; off > 0; off >>= 1) {
        s1 += __shfl_down(s1, off);
        s2 += __shfl_down(s2, off);
    }
    if (l == 0) {
        atomicAdd(&sacc[c0 + lc], s1);
        atomicAdd(&sacc[NCH + c0 + lc], s2);
    }
}

__global__ void finalize(const float* __restrict__ s, float* __restrict__ out) {
    int t = threadIdx.x;
    float v = 0.f;
    if (t < NCH) {
        float s1 = s[t], s2 = s[NCH + t];
        v = (s2 != 0.f) ? (s1 * s1) / s2 : 0.f;
    }
    for (int off = 32; off > 0; off >>= 1) v += __shfl_down(v, off);
    if (t == 0) out[0] = 24.0f - 0.5f * v / 261121.0f;
}

// ---------------- launch ----------------
extern "C" void kernel_launch(void* const* d_in, const int* in_sizes, int n_in,
                              void* d_out, int out_size, void* d_ws, size_t ws_size,
                              hipStream_t stream) {
    const float* recon  = (const float*)d_in[0];
    const float* target = (const float*)d_in[1];
    float* out = (float*)d_out;
    char* ws = (char*)d_ws;

    const size_t OFF_W2F = 0;                        // 524288 B
    const size_t OFF_S   = OFF_W2F + 524288;         // 512 B
    const size_t OFF_X1  = OFF_S + 512;

    u16*   w2f  = (u16*)(ws + OFF_W2F);
    float* sacc = (float*)(ws + OFF_S);
    u16*   x1t  = (u16*)(ws + OFF_X1);

    const size_t perch = 4ull * 65536 * 2;           // 512 KiB per channel
    size_t avail = (ws_size > OFF_X1) ? ws_size - OFF_X1 : 0;
    int chunk = (int)(avail / perch);
    if (chunk > NCH) chunk = NCH;
    if (chunk < 1) chunk = 1;

    setup<<<dim3(1024), dim3(256), 0, stream>>>(w2f, sacc);

    for (int c0 = 0; c0 < NCH; c0 += chunk) {
        int cc = (NCH - c0 < chunk) ? (NCH - c0) : chunk;
        stage1<<<dim3(cc * 4), dim3(256), 0, stream>>>(target, recon, w2f, x1t, c0);
        stage2<<<dim3(cc * 4), dim3(256), 0, stream>>>(x1t, w2f, sacc, c0);
    }
    finalize<<<dim3(1), dim3(64), 0, stream>>>(sacc, out);
}